// Round 2
// baseline (341.925 us; speedup 1.0000x reference)
//
#include <hip/hip_runtime.h>
#include <hip/hip_bf16.h>
#include <math.h>

#define ALPHA 0.2f
#define PB_EDGES 4096   // edges per partition block

typedef __attribute__((ext_vector_type(8))) short short8;
typedef __attribute__((ext_vector_type(4))) float floatx4;

__device__ __forceinline__ ushort f2bf(float f) {
    uint u = __float_as_uint(f);
    u += 0x7fff + ((u >> 16) & 1);   // round-to-nearest-even
    return (ushort)(u >> 16);
}

__device__ __forceinline__ short8 pack8(float4 lo, float4 hi) {
    short8 r;
    r[0] = (short)f2bf(lo.x); r[1] = (short)f2bf(lo.y);
    r[2] = (short)f2bf(lo.z); r[3] = (short)f2bf(lo.w);
    r[4] = (short)f2bf(hi.x); r[5] = (short)f2bf(hi.y);
    r[6] = (short)f2bf(hi.z); r[7] = (short)f2bf(hi.w);
    return r;
}

// ---------------- W prep: Wt[c][d] = bf16(W[h][d][o]), c = h*32+o ----------------
__global__ __launch_bounds__(256) void k_wprep(const float* __restrict__ W,
                                               ushort* __restrict__ Wt)
{
    int g = blockIdx.x * 256 + threadIdx.x;   // g = c*256 + d, 128*256 total
    int c = g >> 8, d = g & 255;
    Wt[g] = f2bf(W[(c >> 5) * 8192 + d * 32 + (c & 31)]);
}

// ---------------- MFMA GEMM + fused f1/f2 epilogue (v2: ILP restructure) ---------
// 128 rows/block, 128 cols, K=256. 4 waves; wave w owns rows w*32..w*32+31
// (2 row-tiles of 16), all 8 col-tiles.
// LDS: Wt in fragment order [ct][ks][lane] * 16B = 64 KB; reused for epilogue.
__global__ __launch_bounds__(256) void k_gemm(const float* __restrict__ x,
                                              const ushort* __restrict__ Wt,
                                              const float* __restrict__ a1v,
                                              const float* __restrict__ b1v,
                                              const float* __restrict__ a2v,
                                              const float* __restrict__ b2v,
                                              ushort* __restrict__ fts2,
                                              float* __restrict__ f1,
                                              float* __restrict__ f2, int M)
{
    __shared__ __align__(16) ushort smem[32768];   // 64 KB
    const int t  = threadIdx.x;
    const int m0 = blockIdx.x * 128;

    // ---- stage Wt -> LDS in fragment order: frag f = ((ct*8+ks)*64 + lane) ----
    // lane = qq*16+mm; source = Wt[(ct*16+mm)*256 + ks*32 + qq*8], 16B per frag.
#pragma unroll
    for (int i = 0; i < 16; i++) {
        int f = i * 256 + t;
        int lane_ = f & 63, ksct = f >> 6;
        int ks = ksct & 7, ct = ksct >> 3;
        int mm = lane_ & 15, qq = lane_ >> 4;
        *(uint4*)&smem[f * 8] = *(const uint4*)&Wt[(ct * 16 + mm) * 256 + ks * 32 + qq * 8];
    }

    const int w = t >> 6, lane = t & 63;
    const int mm = lane & 15, qq = lane >> 4;

    // ---- prefetch + convert A fragments (2 row-tiles x 8 ks), straight from x ----
    int row0 = m0 + w * 32 + mm;
    int row1 = row0 + 16;
    int r0c = (row0 < M) ? row0 : (M - 1);   // clamp (stores are guarded later)
    int r1c = (row1 < M) ? row1 : (M - 1);
    const float* ar0 = x + (size_t)r0c * 256 + qq * 8;
    const float* ar1 = x + (size_t)r1c * 256 + qq * 8;
    short8 afrag[2][8];
#pragma unroll
    for (int ks = 0; ks < 8; ks++) {
        float4 lo0 = *(const float4*)(ar0 + ks * 32);
        float4 hi0 = *(const float4*)(ar0 + ks * 32 + 4);
        float4 lo1 = *(const float4*)(ar1 + ks * 32);
        float4 hi1 = *(const float4*)(ar1 + ks * 32 + 4);
        afrag[0][ks] = pack8(lo0, hi0);
        afrag[1][ks] = pack8(lo1, hi1);
    }

    floatx4 acc[2][8];
#pragma unroll
    for (int r = 0; r < 2; r++)
#pragma unroll
        for (int ct = 0; ct < 8; ct++) acc[r][ct] = (floatx4){0.f, 0.f, 0.f, 0.f};

    __syncthreads();   // Wt staged

    // ---- main loop: pure ds_read_b128 + MFMA ----
#pragma unroll
    for (int ks = 0; ks < 8; ks++) {
#pragma unroll
        for (int ct = 0; ct < 8; ct++) {
            short8 b8 = *(const short8*)&smem[((ct * 8 + ks) * 64 + lane) * 8];
            acc[0][ct] = __builtin_amdgcn_mfma_f32_16x16x32_bf16(afrag[0][ks], b8, acc[0][ct], 0, 0, 0);
            acc[1][ct] = __builtin_amdgcn_mfma_f32_16x16x32_bf16(afrag[1][ks], b8, acc[1][ct], 0, 0, 0);
        }
    }

    __syncthreads();   // done reading Wt; reuse LDS as ftsL[128][136]
    ushort* ftsL = smem;
#pragma unroll
    for (int r = 0; r < 2; r++)
#pragma unroll
        for (int ct = 0; ct < 8; ct++)
#pragma unroll
            for (int i = 0; i < 4; i++) {
                int rowl = w * 32 + r * 16 + qq * 4 + i;   // D: col=lane&15, row=quad*4+reg
                ftsL[rowl * 136 + ct * 16 + mm] = f2bf(acc[r][ct][i]);
            }
    __syncthreads();

    // coalesced bf16 fts2 store: thread -> (row = t>>1, 64-col half = t&1)
    {
        int rowl = t >> 1, half = t & 1;
        int gr = m0 + rowl;
        if (gr < M) {
            const uint4* src = (const uint4*)&ftsL[rowl * 136 + half * 64];
            uint4* dst = (uint4*)(fts2 + (size_t)gr * 128 + half * 64);
#pragma unroll
            for (int i = 0; i < 8; i++) dst[i] = src[i];
        }
    }
    // fused f1/f2: 512 tasks (row, head), 2 per thread
#pragma unroll
    for (int p = 0; p < 2; p++) {
        int task = p * 256 + t;
        int rowl = task >> 2, h = task & 3;
        int gr = m0 + rowl;
        if (gr < M) {
            const ushort* fr = &ftsL[rowl * 136 + h * 32];
            float s1 = 0.f, s2 = 0.f;
#pragma unroll
            for (int o = 0; o < 32; o++) {
                float v = __uint_as_float((uint)fr[o] << 16);
                s1 = fmaf(v, a1v[h * 32 + o], s1);
                s2 = fmaf(v, a2v[h * 32 + o], s2);
            }
            f1[gr * 4 + h] = s1 + b1v[h];
            f2[gr * 4 + h] = s2 + b2v[h];
        }
    }
}

// =============== CSR build via bucketed two-pass sort (NO per-edge global atomics)
__global__ __launch_bounds__(256) void k_phist(const int* __restrict__ erow,
                                               int* __restrict__ bcnt, int E, int NB)
{
    __shared__ int h[512];
    for (int i = threadIdx.x; i < 512; i += 256) h[i] = 0;
    __syncthreads();
    int b0 = blockIdx.x * PB_EDGES;
    int bend = b0 + PB_EDGES; if (bend > E) bend = E;
    for (int j = b0 + threadIdx.x; j < bend; j += 256)
        atomicAdd(&h[erow[j] >> 8], 1);
    __syncthreads();
    for (int i = threadIdx.x; i < NB; i += 256)
        if (h[i]) atomicAdd(&bcnt[i], h[i]);
}

__global__ __launch_bounds__(256) void k_scan_buckets(const int* __restrict__ bcnt,
                                                      int* __restrict__ base,
                                                      int* __restrict__ bcursor,
                                                      int NB, int E)
{
    __shared__ int s[256];
    int t = threadIdx.x;
    int i0 = 2 * t, i1 = 2 * t + 1;
    int v0 = (i0 < NB) ? bcnt[i0] : 0;
    int v1 = (i1 < NB) ? bcnt[i1] : 0;
    int tsum = v0 + v1;
    s[t] = tsum;
    __syncthreads();
    for (int off = 1; off < 256; off <<= 1) {
        int u = (t >= off) ? s[t - off] : 0;
        __syncthreads();
        s[t] += u;
        __syncthreads();
    }
    int excl = s[t] - tsum;
    if (i0 < NB) { base[i0] = excl;      bcursor[i0] = excl; }
    if (i1 < NB) { base[i1] = excl + v0; bcursor[i1] = excl + v0; }
    if (t == 0) base[NB] = E;
}

// partition scatter: packed record ((r&255)<<24) | c  (c < 2^24)
__global__ __launch_bounds__(256) void k_pscatter(const int* __restrict__ erow,
                                                  const int* __restrict__ ecol,
                                                  int* __restrict__ bcursor,
                                                  uint* __restrict__ part, int E)
{
    __shared__ int h[512];
    __shared__ int cur[512];
    for (int i = threadIdx.x; i < 512; i += 256) h[i] = 0;
    __syncthreads();
    int b0 = blockIdx.x * PB_EDGES;
    int bend = b0 + PB_EDGES; if (bend > E) bend = E;
    for (int j = b0 + threadIdx.x; j < bend; j += 256)
        atomicAdd(&h[erow[j] >> 8], 1);
    __syncthreads();
    for (int i = threadIdx.x; i < 512; i += 256)
        cur[i] = h[i] ? atomicAdd(&bcursor[i], h[i]) : 0;
    __syncthreads();
    for (int j = b0 + threadIdx.x; j < bend; j += 256) {
        int r = erow[j], c = ecol[j];
        int p = atomicAdd(&cur[r >> 8], 1);
        part[p] = ((uint)(r & 255) << 24) | (uint)c;
    }
}

__global__ __launch_bounds__(256) void k_bucket(const uint* __restrict__ part,
                                                const int* __restrict__ base,
                                                int* __restrict__ row_start,
                                                int* __restrict__ col_sorted,
                                                int Nn, int NB, int E)
{
    __shared__ int cnt[256];
    __shared__ int s[256];
    __shared__ int cur[256];
    const int b = blockIdx.x, t = threadIdx.x;
    const int start = base[b], end = base[b + 1];

    cnt[t] = 0;
    __syncthreads();
    for (int j = start + t; j < end; j += 256)
        atomicAdd(&cnt[part[j] >> 24], 1);
    __syncthreads();
    int v = cnt[t];
    s[t] = v;
    __syncthreads();
    for (int off = 1; off < 256; off <<= 1) {
        int u = (t >= off) ? s[t - off] : 0;
        __syncthreads();
        s[t] += u;
        __syncthreads();
    }
    int excl = s[t] - v;
    int r = b * 256 + t;
    if (r < Nn) row_start[r] = start + excl;
    if (b == 0 && t == 0) row_start[Nn] = E;
    cur[t] = start + excl;
    __syncthreads();
    for (int j = start + t; j < end; j += 256) {
        uint rc = part[j];
        int p = atomicAdd(&cur[rc >> 24], 1);
        col_sorted[p] = (int)(rc & 0xffffffu);
    }
}

// ---------------- fused segment softmax + SpMM + ELU: one wave per row ------------
// v3: 4 edges per inner wave-instruction.
//   lane = slot*16 + sub : slot = edge-in-group (0..3), sub = 16B chunk of the
//   256B fts2 row (cols sub*8 .. sub*8+7, all within head sub>>2).
//   Outer phase precomputes per-edge exp weights (eL, [edge][head]) and the
//   per-edge fts2 byte offset (vL = c<<8) in LDS; inner loop per 4-edge group:
//   2x ds_read_b32 (imm offsets) + 1x v_add + 1x global_load_dwordx4 (saddr:
//   fts2 < 2^32 bytes) + 8 unpack + 8 fma  ->  ~5 issue-ops/edge vs ~40 before.
__global__ __launch_bounds__(256) void k_gat_row(const ushort* __restrict__ fts2,
                                                 const float4* __restrict__ f1,
                                                 const float4* __restrict__ f2,
                                                 const int* __restrict__ row_start,
                                                 const int* __restrict__ cols,
                                                 float* __restrict__ out, int Nn)
{
    __shared__ __align__(16) float eL[4][256];   // [warp][edge*4 + head]
    __shared__ uint vL[4][64];                   // [warp][edge] = col*256 (byte off)

    const int wid  = threadIdx.x >> 6;
    const int lane = threadIdx.x & 63;
    const int r = blockIdx.x * 4 + wid;
    if (r >= Nn) return;

    const int s = row_start[r], e = row_start[r + 1];

    const int slot = lane >> 4;        // edge within 4-group
    const int sub  = lane & 15;        // 16B chunk within fts2 row
    const int hsel = sub >> 2;         // head owning cols sub*8..sub*8+7

    float4* dst = (float4*)(out + (size_t)r * 128 + sub * 8);
    if (s == e) {
        if (slot == 0) {
            dst[0] = make_float4(0.f, 0.f, 0.f, 0.f);
            dst[1] = make_float4(0.f, 0.f, 0.f, 0.f);
        }
        return;
    }

    const float4 f1r = f1[r];
    float ds0 = 0.f, ds1 = 0.f, ds2 = 0.f, ds3 = 0.f;
    float acc[8];
#pragma unroll
    for (int i = 0; i < 8; i++) acc[i] = 0.f;

    const float* eBase   = &eL[wid][slot * 4 + hsel];
    const uint*  vBase   = &vL[wid][slot];
    const char*  ftsB    = (const char*)fts2;
    const uint   laneOff = (uint)sub * 16;

    for (int j0 = s; j0 < e; j0 += 64) {
        int j = j0 + lane;
        bool act = (j < e);
        int c = act ? cols[j] : 0;
        float4 f2v = f2[c];
        float l0 = f1r.x + f2v.x; l0 = fmaxf(l0, ALPHA * l0);
        float l1 = f1r.y + f2v.y; l1 = fmaxf(l1, ALPHA * l1);
        float l2 = f1r.z + f2v.z; l2 = fmaxf(l2, ALPHA * l2);
        float l3 = f1r.w + f2v.w; l3 = fmaxf(l3, ALPHA * l3);
        float e0 = act ? __expf(l0) : 0.f;
        float e1 = act ? __expf(l1) : 0.f;
        float e2 = act ? __expf(l2) : 0.f;
        float e3 = act ? __expf(l3) : 0.f;
        ds0 += e0; ds1 += e1; ds2 += e2; ds3 += e3;

        asm volatile("s_waitcnt lgkmcnt(0)" ::: "memory");   // prior inner reads done
        ((float4*)eL[wid])[lane] = make_float4(e0, e1, e2, e3);
        vL[wid][lane] = (uint)c << 8;
        asm volatile("s_waitcnt lgkmcnt(0)" ::: "memory");   // writes visible to own reads

        int len = e - j0; if (len > 64) len = 64;
        int ng = (len + 3) >> 2;                // 4-edge groups
#pragma unroll 4
        for (int g = 0; g < ng; g++) {
            float ee = eBase[g * 16];           // e[edge g*4+slot][hsel]
            uint  vo = vBase[g * 4] + laneOff;  // fts2 byte offset (32-bit)
            uint4 vv = *(const uint4*)(ftsB + vo);
            float ve;
            ve = __uint_as_float(vv.x << 16);          acc[0] = fmaf(ee, ve, acc[0]);
            ve = __uint_as_float(vv.x & 0xffff0000u);  acc[1] = fmaf(ee, ve, acc[1]);
            ve = __uint_as_float(vv.y << 16);          acc[2] = fmaf(ee, ve, acc[2]);
            ve = __uint_as_float(vv.y & 0xffff0000u);  acc[3] = fmaf(ee, ve, acc[3]);
            ve = __uint_as_float(vv.z << 16);          acc[4] = fmaf(ee, ve, acc[4]);
            ve = __uint_as_float(vv.z & 0xffff0000u);  acc[5] = fmaf(ee, ve, acc[5]);
            ve = __uint_as_float(vv.w << 16);          acc[6] = fmaf(ee, ve, acc[6]);
            ve = __uint_as_float(vv.w & 0xffff0000u);  acc[7] = fmaf(ee, ve, acc[7]);
        }
    }

    // combine the 4 edge-slot partials (lane^16 flips slot bit0, ^32 flips bit1)
#pragma unroll
    for (int i = 0; i < 8; i++) {
        acc[i] += __shfl_xor(acc[i], 16, 64);
        acc[i] += __shfl_xor(acc[i], 32, 64);
    }
    // denominator reduce (full wave)
#pragma unroll
    for (int off = 32; off > 0; off >>= 1) {
        ds0 += __shfl_xor(ds0, off, 64);
        ds1 += __shfl_xor(ds1, off, 64);
        ds2 += __shfl_xor(ds2, off, 64);
        ds3 += __shfl_xor(ds3, off, 64);
    }
    float dsel = (hsel == 0) ? ds0 : (hsel == 1) ? ds1 : (hsel == 2) ? ds2 : ds3;
    float rinv = 1.0f / dsel;

    float o[8];
#pragma unroll
    for (int i = 0; i < 8; i++) {
        float v = acc[i] * rinv;
        o[i] = (v > 0.f) ? v : (__expf(v) - 1.0f);
    }
    if (slot == 0) {
        dst[0] = make_float4(o[0], o[1], o[2], o[3]);
        dst[1] = make_float4(o[4], o[5], o[6], o[7]);
    }
}

// ---------------------------------------------------------------------------------
extern "C" void kernel_launch(void* const* d_in, const int* in_sizes, int n_in,
                              void* d_out, int out_size, void* d_ws, size_t ws_size,
                              hipStream_t stream)
{
    const float* x   = (const float*)d_in[0];
    const float* W   = (const float*)d_in[1];
    const float* a1  = (const float*)d_in[2];
    const float* b1  = (const float*)d_in[3];
    const float* a2  = (const float*)d_in[4];
    const float* b2  = (const float*)d_in[5];
    const int*   erow = (const int*)d_in[6];
    const int*   ecol = (const int*)d_in[7];
    float* out = (float*)d_out;

    const int N = in_sizes[0] / 256;   // 100000
    const int E = in_sizes[6];         // 1600000
    const int NB = (N + 255) >> 8;

    char*  ws  = (char*)d_ws;
    size_t off = 0;
    auto carve = [&](size_t bytes) -> char* {
        char* p = ws + off;
        off += (bytes + 255) & ~(size_t)255;
        return p;
    };
    ushort* fts2      = (ushort*)carve((size_t)N * 128 * 2);
    ushort* Wt        = (ushort*)carve((size_t)128 * 256 * 2);
    float*  f1        = (float*)carve((size_t)N * 4 * 4);
    float*  f2        = (float*)carve((size_t)N * 4 * 4);
    int*    row_start = (int*)carve(((size_t)N + 1) * 4);
    int*    bcnt      = (int*)carve(512 * 4);
    int*    base      = (int*)carve(513 * 4);
    int*    bcursor   = (int*)carve(512 * 4);
    int*    col_sorted= (int*)carve((size_t)E * 4);
    uint*   part      = (uint*)carve((size_t)E * 4);
    (void)ws_size;

    k_wprep<<<128, 256, 0, stream>>>(W, Wt);
    k_gemm<<<(N + 127) / 128, 256, 0, stream>>>(x, Wt, a1, b1, a2, b2, fts2, f1, f2, N);

    hipMemsetAsync(bcnt, 0, 512 * 4, stream);
    int npb = (E + PB_EDGES - 1) / PB_EDGES;
    k_phist<<<npb, 256, 0, stream>>>(erow, bcnt, E, NB);
    k_scan_buckets<<<1, 256, 0, stream>>>(bcnt, base, bcursor, NB, E);
    k_pscatter<<<npb, 256, 0, stream>>>(erow, ecol, bcursor, part, E);
    k_bucket<<<NB, 256, 0, stream>>>(part, base, row_start, col_sorted, N, NB, E);

    k_gat_row<<<(N + 3) / 4, 256, 0, stream>>>(fts2, (const float4*)f1, (const float4*)f2,
                                               row_start, col_sorted, out, N);
}

// Round 3
// 337.264 us; speedup vs baseline: 1.0138x; 1.0138x over previous
//
#include <hip/hip_runtime.h>
#include <hip/hip_bf16.h>
#include <math.h>

#define ALPHA 0.2f
#define PB_EDGES 4096   // edges per partition block
#define MAXT 256        // edge-chunk per wave (4 rows, mean T=64; chunk loop handles tails)

typedef __attribute__((ext_vector_type(8))) short short8;
typedef __attribute__((ext_vector_type(4))) float floatx4;

__device__ __forceinline__ ushort f2bf(float f) {
    uint u = __float_as_uint(f);
    u += 0x7fff + ((u >> 16) & 1);   // round-to-nearest-even
    return (ushort)(u >> 16);
}

__device__ __forceinline__ short8 pack8(float4 lo, float4 hi) {
    short8 r;
    r[0] = (short)f2bf(lo.x); r[1] = (short)f2bf(lo.y);
    r[2] = (short)f2bf(lo.z); r[3] = (short)f2bf(lo.w);
    r[4] = (short)f2bf(hi.x); r[5] = (short)f2bf(hi.y);
    r[6] = (short)f2bf(hi.z); r[7] = (short)f2bf(hi.w);
    return r;
}

// ---------------- W prep: Wt[c][d] = bf16(W[h][d][o]), c = h*32+o ----------------
__global__ __launch_bounds__(256) void k_wprep(const float* __restrict__ W,
                                               ushort* __restrict__ Wt)
{
    int g = blockIdx.x * 256 + threadIdx.x;   // g = c*256 + d, 128*256 total
    int c = g >> 8, d = g & 255;
    Wt[g] = f2bf(W[(c >> 5) * 8192 + d * 32 + (c & 31)]);
}

// ---------------- MFMA GEMM + fused f1/f2 epilogue ---------
__global__ __launch_bounds__(256) void k_gemm(const float* __restrict__ x,
                                              const ushort* __restrict__ Wt,
                                              const float* __restrict__ a1v,
                                              const float* __restrict__ b1v,
                                              const float* __restrict__ a2v,
                                              const float* __restrict__ b2v,
                                              ushort* __restrict__ fts2,
                                              float* __restrict__ f1,
                                              float* __restrict__ f2, int M)
{
    __shared__ __align__(16) ushort smem[32768];   // 64 KB
    const int t  = threadIdx.x;
    const int m0 = blockIdx.x * 128;

#pragma unroll
    for (int i = 0; i < 16; i++) {
        int f = i * 256 + t;
        int lane_ = f & 63, ksct = f >> 6;
        int ks = ksct & 7, ct = ksct >> 3;
        int mm = lane_ & 15, qq = lane_ >> 4;
        *(uint4*)&smem[f * 8] = *(const uint4*)&Wt[(ct * 16 + mm) * 256 + ks * 32 + qq * 8];
    }

    const int w = t >> 6, lane = t & 63;
    const int mm = lane & 15, qq = lane >> 4;

    int row0 = m0 + w * 32 + mm;
    int row1 = row0 + 16;
    int r0c = (row0 < M) ? row0 : (M - 1);
    int r1c = (row1 < M) ? row1 : (M - 1);
    const float* ar0 = x + (size_t)r0c * 256 + qq * 8;
    const float* ar1 = x + (size_t)r1c * 256 + qq * 8;
    short8 afrag[2][8];
#pragma unroll
    for (int ks = 0; ks < 8; ks++) {
        float4 lo0 = *(const float4*)(ar0 + ks * 32);
        float4 hi0 = *(const float4*)(ar0 + ks * 32 + 4);
        float4 lo1 = *(const float4*)(ar1 + ks * 32);
        float4 hi1 = *(const float4*)(ar1 + ks * 32 + 4);
        afrag[0][ks] = pack8(lo0, hi0);
        afrag[1][ks] = pack8(lo1, hi1);
    }

    floatx4 acc[2][8];
#pragma unroll
    for (int r = 0; r < 2; r++)
#pragma unroll
        for (int ct = 0; ct < 8; ct++) acc[r][ct] = (floatx4){0.f, 0.f, 0.f, 0.f};

    __syncthreads();   // Wt staged

#pragma unroll
    for (int ks = 0; ks < 8; ks++) {
#pragma unroll
        for (int ct = 0; ct < 8; ct++) {
            short8 b8 = *(const short8*)&smem[((ct * 8 + ks) * 64 + lane) * 8];
            acc[0][ct] = __builtin_amdgcn_mfma_f32_16x16x32_bf16(afrag[0][ks], b8, acc[0][ct], 0, 0, 0);
            acc[1][ct] = __builtin_amdgcn_mfma_f32_16x16x32_bf16(afrag[1][ks], b8, acc[1][ct], 0, 0, 0);
        }
    }

    __syncthreads();   // done reading Wt; reuse LDS as ftsL[128][136]
    ushort* ftsL = smem;
#pragma unroll
    for (int r = 0; r < 2; r++)
#pragma unroll
        for (int ct = 0; ct < 8; ct++)
#pragma unroll
            for (int i = 0; i < 4; i++) {
                int rowl = w * 32 + r * 16 + qq * 4 + i;   // D: col=lane&15, row=quad*4+reg
                ftsL[rowl * 136 + ct * 16 + mm] = f2bf(acc[r][ct][i]);
            }
    __syncthreads();

    {
        int rowl = t >> 1, half = t & 1;
        int gr = m0 + rowl;
        if (gr < M) {
            const uint4* src = (const uint4*)&ftsL[rowl * 136 + half * 64];
            uint4* dst = (uint4*)(fts2 + (size_t)gr * 128 + half * 64);
#pragma unroll
            for (int i = 0; i < 8; i++) dst[i] = src[i];
        }
    }
#pragma unroll
    for (int p = 0; p < 2; p++) {
        int task = p * 256 + t;
        int rowl = task >> 2, h = task & 3;
        int gr = m0 + rowl;
        if (gr < M) {
            const ushort* fr = &ftsL[rowl * 136 + h * 32];
            float s1 = 0.f, s2 = 0.f;
#pragma unroll
            for (int o = 0; o < 32; o++) {
                float v = __uint_as_float((uint)fr[o] << 16);
                s1 = fmaf(v, a1v[h * 32 + o], s1);
                s2 = fmaf(v, a2v[h * 32 + o], s2);
            }
            f1[gr * 4 + h] = s1 + b1v[h];
            f2[gr * 4 + h] = s2 + b2v[h];
        }
    }
}

// =============== CSR build via bucketed two-pass sort (NO per-edge global atomics)
__global__ __launch_bounds__(256) void k_phist(const int* __restrict__ erow,
                                               int* __restrict__ bcnt, int E, int NB)
{
    __shared__ int h[512];
    for (int i = threadIdx.x; i < 512; i += 256) h[i] = 0;
    __syncthreads();
    int b0 = blockIdx.x * PB_EDGES;
    int bend = b0 + PB_EDGES; if (bend > E) bend = E;
    for (int j = b0 + threadIdx.x; j < bend; j += 256)
        atomicAdd(&h[erow[j] >> 8], 1);
    __syncthreads();
    for (int i = threadIdx.x; i < NB; i += 256)
        if (h[i]) atomicAdd(&bcnt[i], h[i]);
}

__global__ __launch_bounds__(256) void k_scan_buckets(const int* __restrict__ bcnt,
                                                      int* __restrict__ base,
                                                      int* __restrict__ bcursor,
                                                      int NB, int E)
{
    __shared__ int s[256];
    int t = threadIdx.x;
    int i0 = 2 * t, i1 = 2 * t + 1;
    int v0 = (i0 < NB) ? bcnt[i0] : 0;
    int v1 = (i1 < NB) ? bcnt[i1] : 0;
    int tsum = v0 + v1;
    s[t] = tsum;
    __syncthreads();
    for (int off = 1; off < 256; off <<= 1) {
        int u = (t >= off) ? s[t - off] : 0;
        __syncthreads();
        s[t] += u;
        __syncthreads();
    }
    int excl = s[t] - tsum;
    if (i0 < NB) { base[i0] = excl;      bcursor[i0] = excl; }
    if (i1 < NB) { base[i1] = excl + v0; bcursor[i1] = excl + v0; }
    if (t == 0) base[NB] = E;
}

// partition scatter: packed record ((r&255)<<24) | c  (c < 2^24)
__global__ __launch_bounds__(256) void k_pscatter(const int* __restrict__ erow,
                                                  const int* __restrict__ ecol,
                                                  int* __restrict__ bcursor,
                                                  uint* __restrict__ part, int E)
{
    __shared__ int h[512];
    __shared__ int cur[512];
    for (int i = threadIdx.x; i < 512; i += 256) h[i] = 0;
    __syncthreads();
    int b0 = blockIdx.x * PB_EDGES;
    int bend = b0 + PB_EDGES; if (bend > E) bend = E;
    for (int j = b0 + threadIdx.x; j < bend; j += 256)
        atomicAdd(&h[erow[j] >> 8], 1);
    __syncthreads();
    for (int i = threadIdx.x; i < 512; i += 256)
        cur[i] = h[i] ? atomicAdd(&bcursor[i], h[i]) : 0;
    __syncthreads();
    for (int j = b0 + threadIdx.x; j < bend; j += 256) {
        int r = erow[j], c = ecol[j];
        int p = atomicAdd(&cur[r >> 8], 1);
        part[p] = ((uint)(r & 255) << 24) | (uint)c;
    }
}

__global__ __launch_bounds__(256) void k_bucket(const uint* __restrict__ part,
                                                const int* __restrict__ base,
                                                int* __restrict__ row_start,
                                                int* __restrict__ col_sorted,
                                                int Nn, int NB, int E)
{
    __shared__ int cnt[256];
    __shared__ int s[256];
    __shared__ int cur[256];
    const int b = blockIdx.x, t = threadIdx.x;
    const int start = base[b], end = base[b + 1];

    cnt[t] = 0;
    __syncthreads();
    for (int j = start + t; j < end; j += 256)
        atomicAdd(&cnt[part[j] >> 24], 1);
    __syncthreads();
    int v = cnt[t];
    s[t] = v;
    __syncthreads();
    for (int off = 1; off < 256; off <<= 1) {
        int u = (t >= off) ? s[t - off] : 0;
        __syncthreads();
        s[t] += u;
        __syncthreads();
    }
    int excl = s[t] - v;
    int r = b * 256 + t;
    if (r < Nn) row_start[r] = start + excl;
    if (b == 0 && t == 0) row_start[Nn] = E;
    cur[t] = start + excl;
    __syncthreads();
    for (int j = start + t; j < end; j += 256) {
        uint rc = part[j];
        int p = atomicAdd(&cur[rc >> 24], 1);
        col_sorted[p] = (int)(rc & 0xffffffu);
    }
}

// ---------------- fused segment softmax + SpMM + ELU ------------------------------
// v4: wave = 4 consecutive rows (slot = lane>>4), 16 lanes per row.
//   Mean in-degree = 16, so the 4 rows' contiguous CSR range has mean T = 64:
//   Phase A (load cols, gather f2, exp, stage to LDS) runs at FULL 64-lane
//   utilization (v3 ran it at ~16/64 active for typical rows).
//   Lane = slot*16 + sub: lane owns the 16B slice (8 cols, one head) of its
//   slot's row. Phase B: each slot walks its own edge range; lane accumulates
//   acc[8] (fma) and ds += ee. Since every edge of the row passes through the
//   lane, ds ends as the COMPLETE softmax denominator for the lane's head:
//   the full-wave swizzle reductions and slot-combine of v3 vanish entirely.
__global__ __launch_bounds__(256) void k_gat_row(const ushort* __restrict__ fts2,
                                                 const float4* __restrict__ f1,
                                                 const float4* __restrict__ f2,
                                                 const int* __restrict__ row_start,
                                                 const int* __restrict__ cols,
                                                 float* __restrict__ out, int Nn)
{
    __shared__ __align__(16) float eLs[4][MAXT * 4];   // [wave][edge*4+head], 16KB
    __shared__ uint vLs[4][MAXT];                      // [wave][edge] = col*256, 4KB

    const int wid  = threadIdx.x >> 6;
    const int lane = threadIdx.x & 63;
    const int slot = lane >> 4;        // which of the wave's 4 rows
    const int sub  = lane & 15;        // 16B slice of the 256B fts2 row
    const int hsel = sub >> 2;         // head owning cols sub*8..sub*8+7

    const int rbase = (blockIdx.x * 4 + wid) * 4;
    if (rbase >= Nn) return;

    const int myr = rbase + slot;
    const bool rowAct = (myr < Nn);
    const int i0 = rowAct ? myr : Nn;
    const int i1 = (myr + 1 < Nn) ? (myr + 1) : Nn;
    const int sB = row_start[i0];
    const int eB = row_start[i1];
    const int degTot = eB - sB;

    // wave-uniform range + row boundaries
    const int s0 = __shfl(sB, 0, 64);
    const int b1 = __shfl(sB, 16, 64);
    const int b2 = __shfl(sB, 32, 64);
    const int b3 = __shfl(sB, 48, 64);
    const int T  = __shfl(eB, 48, 64) - s0;

    float ds = 0.f;
    float acc[8];
#pragma unroll
    for (int i = 0; i < 8; i++) acc[i] = 0.f;

    const char* ftsB = (const char*)fts2;
    const uint  laneOff = (uint)sub * 16;
    float* eLw = eLs[wid];
    uint*  vLw = vLs[wid];

    for (int base = 0; base < T; base += MAXT) {
        int tc = T - base; if (tc > MAXT) tc = MAXT;
        int tcPad = (tc + 63) & ~63;

        // ---- Phase A: stage exp weights + byte offsets for tc edges ----
        for (int lt = lane; lt < tcPad; lt += 64) {
            bool act = (lt < tc);
            int j = s0 + base + lt;
            int c = act ? cols[j] : 0;
            int rsel = (j >= b1) + (j >= b2) + (j >= b3);
            int fi = rbase + rsel; if (fi >= Nn) fi = Nn - 1;
            float4 f1r = f1[fi];
            float4 f2v = f2[c];
            float l0 = f1r.x + f2v.x; l0 = fmaxf(l0, ALPHA * l0);
            float l1 = f1r.y + f2v.y; l1 = fmaxf(l1, ALPHA * l1);
            float l2 = f1r.z + f2v.z; l2 = fmaxf(l2, ALPHA * l2);
            float l3 = f1r.w + f2v.w; l3 = fmaxf(l3, ALPHA * l3);
            float e0 = act ? __expf(l0) : 0.f;
            float e1 = act ? __expf(l1) : 0.f;
            float e2 = act ? __expf(l2) : 0.f;
            float e3 = act ? __expf(l3) : 0.f;
            asm volatile("s_waitcnt lgkmcnt(0)" ::: "memory");  // prior-chunk reads done
            *(float4*)&eLw[lt * 4] = make_float4(e0, e1, e2, e3);
            vLw[lt] = (uint)c << 8;
        }
        asm volatile("s_waitcnt lgkmcnt(0)" ::: "memory");      // stage visible

        // ---- Phase B: per-slot edge walk (divergent trip; masked lanes fetch nothing)
        int lo = sB - s0 - base; lo = (lo < 0) ? 0 : ((lo > tc) ? tc : lo);
        int hi = eB - s0 - base; hi = (hi < 0) ? 0 : ((hi > tc) ? tc : hi);
        int ni = hi - lo;
        int eIdx = lo * 4 + hsel;
#pragma unroll 4
        for (int g = 0; g < ni; g++) {
            float ee = eLw[eIdx + g * 4];
            uint  vo = vLw[lo + g] + laneOff;
            uint4 vv = *(const uint4*)(ftsB + vo);
            ds += ee;
            float ve;
            ve = __uint_as_float(vv.x << 16);          acc[0] = fmaf(ee, ve, acc[0]);
            ve = __uint_as_float(vv.x & 0xffff0000u);  acc[1] = fmaf(ee, ve, acc[1]);
            ve = __uint_as_float(vv.y << 16);          acc[2] = fmaf(ee, ve, acc[2]);
            ve = __uint_as_float(vv.y & 0xffff0000u);  acc[3] = fmaf(ee, ve, acc[3]);
            ve = __uint_as_float(vv.z << 16);          acc[4] = fmaf(ee, ve, acc[4]);
            ve = __uint_as_float(vv.z & 0xffff0000u);  acc[5] = fmaf(ee, ve, acc[5]);
            ve = __uint_as_float(vv.w << 16);          acc[6] = fmaf(ee, ve, acc[6]);
            ve = __uint_as_float(vv.w & 0xffff0000u);  acc[7] = fmaf(ee, ve, acc[7]);
        }
    }

    // ---- epilogue: no cross-lane reduction needed; ds is the full denominator ----
    float dsel = (degTot > 0) ? ds : 1.f;
    float rinv = 1.0f / dsel;
    float o[8];
#pragma unroll
    for (int i = 0; i < 8; i++) {
        float v = acc[i] * rinv;
        o[i] = (v > 0.f) ? v : (__expf(v) - 1.0f);
    }
    if (rowAct) {
        float4* dst = (float4*)(out + (size_t)myr * 128 + sub * 8);
        dst[0] = make_float4(o[0], o[1], o[2], o[3]);
        dst[1] = make_float4(o[4], o[5], o[6], o[7]);
    }
}

// ---------------------------------------------------------------------------------
extern "C" void kernel_launch(void* const* d_in, const int* in_sizes, int n_in,
                              void* d_out, int out_size, void* d_ws, size_t ws_size,
                              hipStream_t stream)
{
    const float* x   = (const float*)d_in[0];
    const float* W   = (const float*)d_in[1];
    const float* a1  = (const float*)d_in[2];
    const float* b1  = (const float*)d_in[3];
    const float* a2  = (const float*)d_in[4];
    const float* b2  = (const float*)d_in[5];
    const int*   erow = (const int*)d_in[6];
    const int*   ecol = (const int*)d_in[7];
    float* out = (float*)d_out;

    const int N = in_sizes[0] / 256;   // 100000
    const int E = in_sizes[6];         // 1600000
    const int NB = (N + 255) >> 8;

    char*  ws  = (char*)d_ws;
    size_t off = 0;
    auto carve = [&](size_t bytes) -> char* {
        char* p = ws + off;
        off += (bytes + 255) & ~(size_t)255;
        return p;
    };
    ushort* fts2      = (ushort*)carve((size_t)N * 128 * 2);
    ushort* Wt        = (ushort*)carve((size_t)128 * 256 * 2);
    float*  f1        = (float*)carve((size_t)N * 4 * 4);
    float*  f2        = (float*)carve((size_t)N * 4 * 4);
    int*    row_start = (int*)carve(((size_t)N + 1) * 4);
    int*    bcnt      = (int*)carve(512 * 4);
    int*    base      = (int*)carve(513 * 4);
    int*    bcursor   = (int*)carve(512 * 4);
    int*    col_sorted= (int*)carve((size_t)E * 4);
    uint*   part      = (uint*)carve((size_t)E * 4);
    (void)ws_size;

    k_wprep<<<128, 256, 0, stream>>>(W, Wt);
    k_gemm<<<(N + 127) / 128, 256, 0, stream>>>(x, Wt, a1, b1, a2, b2, fts2, f1, f2, N);

    hipMemsetAsync(bcnt, 0, 512 * 4, stream);
    int npb = (E + PB_EDGES - 1) / PB_EDGES;
    k_phist<<<npb, 256, 0, stream>>>(erow, bcnt, E, NB);
    k_scan_buckets<<<1, 256, 0, stream>>>(bcnt, base, bcursor, NB, E);
    k_pscatter<<<npb, 256, 0, stream>>>(erow, ecol, bcursor, part, E);
    k_bucket<<<NB, 256, 0, stream>>>(part, base, row_start, col_sorted, N, NB, E);

    // 16 rows per block (4 waves x 4 rows)
    k_gat_row<<<(N + 15) / 16, 256, 0, stream>>>(fts2, (const float4*)f1, (const float4*)f2,
                                                 row_start, col_sorted, out, N);
}

// Round 4
// 332.799 us; speedup vs baseline: 1.0274x; 1.0134x over previous
//
#include <hip/hip_runtime.h>
#include <hip/hip_bf16.h>
#include <math.h>

#define ALPHA 0.2f
#define PB_EDGES 4096   // edges per partition block
#define MAXT 128        // edge-chunk per wave (4 rows, mean T=64; chunk loop handles tails)

typedef __attribute__((ext_vector_type(8))) short short8;
typedef __attribute__((ext_vector_type(4))) float floatx4;

__device__ __forceinline__ ushort f2bf(float f) {
    uint u = __float_as_uint(f);
    u += 0x7fff + ((u >> 16) & 1);   // round-to-nearest-even
    return (ushort)(u >> 16);
}

__device__ __forceinline__ short8 pack8(float4 lo, float4 hi) {
    short8 r;
    r[0] = (short)f2bf(lo.x); r[1] = (short)f2bf(lo.y);
    r[2] = (short)f2bf(lo.z); r[3] = (short)f2bf(lo.w);
    r[4] = (short)f2bf(hi.x); r[5] = (short)f2bf(hi.y);
    r[6] = (short)f2bf(hi.z); r[7] = (short)f2bf(hi.w);
    return r;
}

// ---------------- W prep: Wt[c][d] = bf16(W[h][d][o]), c = h*32+o ----------------
__global__ __launch_bounds__(256) void k_wprep(const float* __restrict__ W,
                                               ushort* __restrict__ Wt)
{
    int g = blockIdx.x * 256 + threadIdx.x;   // g = c*256 + d, 128*256 total
    int c = g >> 8, d = g & 255;
    Wt[g] = f2bf(W[(c >> 5) * 8192 + d * 32 + (c & 31)]);
}

// ---------------- MFMA GEMM + fused f1/f2 epilogue ---------
__global__ __launch_bounds__(256) void k_gemm(const float* __restrict__ x,
                                              const ushort* __restrict__ Wt,
                                              const float* __restrict__ a1v,
                                              const float* __restrict__ b1v,
                                              const float* __restrict__ a2v,
                                              const float* __restrict__ b2v,
                                              ushort* __restrict__ fts2,
                                              float* __restrict__ f1,
                                              float* __restrict__ f2, int M)
{
    __shared__ __align__(16) ushort smem[32768];   // 64 KB
    const int t  = threadIdx.x;
    const int m0 = blockIdx.x * 128;

#pragma unroll
    for (int i = 0; i < 16; i++) {
        int f = i * 256 + t;
        int lane_ = f & 63, ksct = f >> 6;
        int ks = ksct & 7, ct = ksct >> 3;
        int mm = lane_ & 15, qq = lane_ >> 4;
        *(uint4*)&smem[f * 8] = *(const uint4*)&Wt[(ct * 16 + mm) * 256 + ks * 32 + qq * 8];
    }

    const int w = t >> 6, lane = t & 63;
    const int mm = lane & 15, qq = lane >> 4;

    int row0 = m0 + w * 32 + mm;
    int row1 = row0 + 16;
    int r0c = (row0 < M) ? row0 : (M - 1);
    int r1c = (row1 < M) ? row1 : (M - 1);
    const float* ar0 = x + (size_t)r0c * 256 + qq * 8;
    const float* ar1 = x + (size_t)r1c * 256 + qq * 8;
    short8 afrag[2][8];
#pragma unroll
    for (int ks = 0; ks < 8; ks++) {
        float4 lo0 = *(const float4*)(ar0 + ks * 32);
        float4 hi0 = *(const float4*)(ar0 + ks * 32 + 4);
        float4 lo1 = *(const float4*)(ar1 + ks * 32);
        float4 hi1 = *(const float4*)(ar1 + ks * 32 + 4);
        afrag[0][ks] = pack8(lo0, hi0);
        afrag[1][ks] = pack8(lo1, hi1);
    }

    floatx4 acc[2][8];
#pragma unroll
    for (int r = 0; r < 2; r++)
#pragma unroll
        for (int ct = 0; ct < 8; ct++) acc[r][ct] = (floatx4){0.f, 0.f, 0.f, 0.f};

    __syncthreads();   // Wt staged

#pragma unroll
    for (int ks = 0; ks < 8; ks++) {
#pragma unroll
        for (int ct = 0; ct < 8; ct++) {
            short8 b8 = *(const short8*)&smem[((ct * 8 + ks) * 64 + lane) * 8];
            acc[0][ct] = __builtin_amdgcn_mfma_f32_16x16x32_bf16(afrag[0][ks], b8, acc[0][ct], 0, 0, 0);
            acc[1][ct] = __builtin_amdgcn_mfma_f32_16x16x32_bf16(afrag[1][ks], b8, acc[1][ct], 0, 0, 0);
        }
    }

    __syncthreads();   // done reading Wt; reuse LDS as ftsL[128][136]
    ushort* ftsL = smem;
#pragma unroll
    for (int r = 0; r < 2; r++)
#pragma unroll
        for (int ct = 0; ct < 8; ct++)
#pragma unroll
            for (int i = 0; i < 4; i++) {
                int rowl = w * 32 + r * 16 + qq * 4 + i;   // D: col=lane&15, row=quad*4+reg
                ftsL[rowl * 136 + ct * 16 + mm] = f2bf(acc[r][ct][i]);
            }
    __syncthreads();

    {
        int rowl = t >> 1, half = t & 1;
        int gr = m0 + rowl;
        if (gr < M) {
            const uint4* src = (const uint4*)&ftsL[rowl * 136 + half * 64];
            uint4* dst = (uint4*)(fts2 + (size_t)gr * 128 + half * 64);
#pragma unroll
            for (int i = 0; i < 8; i++) dst[i] = src[i];
        }
    }
#pragma unroll
    for (int p = 0; p < 2; p++) {
        int task = p * 256 + t;
        int rowl = task >> 2, h = task & 3;
        int gr = m0 + rowl;
        if (gr < M) {
            const ushort* fr = &ftsL[rowl * 136 + h * 32];
            float s1 = 0.f, s2 = 0.f;
#pragma unroll
            for (int o = 0; o < 32; o++) {
                float v = __uint_as_float((uint)fr[o] << 16);
                s1 = fmaf(v, a1v[h * 32 + o], s1);
                s2 = fmaf(v, a2v[h * 32 + o], s2);
            }
            f1[gr * 4 + h] = s1 + b1v[h];
            f2[gr * 4 + h] = s2 + b2v[h];
        }
    }
}

// =============== CSR build via bucketed two-pass sort (NO per-edge global atomics)
__global__ __launch_bounds__(256) void k_phist(const int* __restrict__ erow,
                                               int* __restrict__ bcnt, int E, int NB)
{
    __shared__ int h[512];
    for (int i = threadIdx.x; i < 512; i += 256) h[i] = 0;
    __syncthreads();
    int b0 = blockIdx.x * PB_EDGES;
    int bend = b0 + PB_EDGES; if (bend > E) bend = E;
    for (int j = b0 + threadIdx.x; j < bend; j += 256)
        atomicAdd(&h[erow[j] >> 8], 1);
    __syncthreads();
    for (int i = threadIdx.x; i < NB; i += 256)
        if (h[i]) atomicAdd(&bcnt[i], h[i]);
}

__global__ __launch_bounds__(256) void k_scan_buckets(const int* __restrict__ bcnt,
                                                      int* __restrict__ base,
                                                      int* __restrict__ bcursor,
                                                      int NB, int E)
{
    __shared__ int s[256];
    int t = threadIdx.x;
    int i0 = 2 * t, i1 = 2 * t + 1;
    int v0 = (i0 < NB) ? bcnt[i0] : 0;
    int v1 = (i1 < NB) ? bcnt[i1] : 0;
    int tsum = v0 + v1;
    s[t] = tsum;
    __syncthreads();
    for (int off = 1; off < 256; off <<= 1) {
        int u = (t >= off) ? s[t - off] : 0;
        __syncthreads();
        s[t] += u;
        __syncthreads();
    }
    int excl = s[t] - tsum;
    if (i0 < NB) { base[i0] = excl;      bcursor[i0] = excl; }
    if (i1 < NB) { base[i1] = excl + v0; bcursor[i1] = excl + v0; }
    if (t == 0) base[NB] = E;
}

// partition scatter: packed record ((r&255)<<24) | c  (c < 2^24)
__global__ __launch_bounds__(256) void k_pscatter(const int* __restrict__ erow,
                                                  const int* __restrict__ ecol,
                                                  int* __restrict__ bcursor,
                                                  uint* __restrict__ part, int E)
{
    __shared__ int h[512];
    __shared__ int cur[512];
    for (int i = threadIdx.x; i < 512; i += 256) h[i] = 0;
    __syncthreads();
    int b0 = blockIdx.x * PB_EDGES;
    int bend = b0 + PB_EDGES; if (bend > E) bend = E;
    for (int j = b0 + threadIdx.x; j < bend; j += 256)
        atomicAdd(&h[erow[j] >> 8], 1);
    __syncthreads();
    for (int i = threadIdx.x; i < 512; i += 256)
        cur[i] = h[i] ? atomicAdd(&bcursor[i], h[i]) : 0;
    __syncthreads();
    for (int j = b0 + threadIdx.x; j < bend; j += 256) {
        int r = erow[j], c = ecol[j];
        int p = atomicAdd(&cur[r >> 8], 1);
        part[p] = ((uint)(r & 255) << 24) | (uint)c;
    }
}

__global__ __launch_bounds__(256) void k_bucket(const uint* __restrict__ part,
                                                const int* __restrict__ base,
                                                int* __restrict__ row_start,
                                                int* __restrict__ col_sorted,
                                                int Nn, int NB, int E)
{
    __shared__ int cnt[256];
    __shared__ int s[256];
    __shared__ int cur[256];
    const int b = blockIdx.x, t = threadIdx.x;
    const int start = base[b], end = base[b + 1];

    cnt[t] = 0;
    __syncthreads();
    for (int j = start + t; j < end; j += 256)
        atomicAdd(&cnt[part[j] >> 24], 1);
    __syncthreads();
    int v = cnt[t];
    s[t] = v;
    __syncthreads();
    for (int off = 1; off < 256; off <<= 1) {
        int u = (t >= off) ? s[t - off] : 0;
        __syncthreads();
        s[t] += u;
        __syncthreads();
    }
    int excl = s[t] - v;
    int r = b * 256 + t;
    if (r < Nn) row_start[r] = start + excl;
    if (b == 0 && t == 0) row_start[Nn] = E;
    cur[t] = start + excl;
    __syncthreads();
    for (int j = start + t; j < end; j += 256) {
        uint rc = part[j];
        int p = atomicAdd(&cur[rc >> 24], 1);
        col_sorted[p] = (int)(rc & 0xffffffu);
    }
}

// ---------------- fused segment softmax + SpMM + ELU ------------------------------
// v5: wave = 4 consecutive rows (slot = lane>>4), 16 lanes per row.
//   Phase A at full 64-lane utilization (contiguous 4-row CSR range, mean T=64).
//   Phase B: DUAL independent edge streams per lane (even/odd edges of the
//   slot's list) with separate accumulator sets -> 2x memory-level parallelism
//   and half the dependent-chain length; the gather is an L2-miss/L3-hit
//   (~450cy) and round-3 counters (VALU 29%, HBM 44%, occ 65%) showed
//   latency-boundedness. MAXT 256->128 cuts LDS 20KB->10KB for occupancy
//   headroom. Lane ds accumulation = complete per-head denominator (no
//   cross-lane reduction).
__global__ __launch_bounds__(256) void k_gat_row(const ushort* __restrict__ fts2,
                                                 const float4* __restrict__ f1,
                                                 const float4* __restrict__ f2,
                                                 const int* __restrict__ row_start,
                                                 const int* __restrict__ cols,
                                                 float* __restrict__ out, int Nn)
{
    __shared__ __align__(16) float eLs[4][MAXT * 4];   // [wave][edge*4+head], 8KB
    __shared__ uint vLs[4][MAXT];                      // [wave][edge] = col*256, 2KB

    const int wid  = threadIdx.x >> 6;
    const int lane = threadIdx.x & 63;
    const int slot = lane >> 4;        // which of the wave's 4 rows
    const int sub  = lane & 15;        // 16B slice of the 256B fts2 row
    const int hsel = sub >> 2;         // head owning cols sub*8..sub*8+7

    const int rbase = (blockIdx.x * 4 + wid) * 4;
    if (rbase >= Nn) return;

    const int myr = rbase + slot;
    const bool rowAct = (myr < Nn);
    const int i0 = rowAct ? myr : Nn;
    const int i1 = (myr + 1 < Nn) ? (myr + 1) : Nn;
    const int sB = row_start[i0];
    const int eB = row_start[i1];
    const int degTot = eB - sB;

    // wave-uniform range + row boundaries
    const int s0 = __shfl(sB, 0, 64);
    const int b1 = __shfl(sB, 16, 64);
    const int b2 = __shfl(sB, 32, 64);
    const int b3 = __shfl(sB, 48, 64);
    const int T  = __shfl(eB, 48, 64) - s0;

    float dsA = 0.f, dsB = 0.f;
    float accA[8], accB[8];
#pragma unroll
    for (int i = 0; i < 8; i++) { accA[i] = 0.f; accB[i] = 0.f; }

    const char* ftsB = (const char*)fts2;
    const uint  laneOff = (uint)sub * 16;
    float* eLw = eLs[wid];
    uint*  vLw = vLs[wid];

    for (int base = 0; base < T; base += MAXT) {
        int tc = T - base; if (tc > MAXT) tc = MAXT;
        int tcPad = (tc + 63) & ~63;

        // ---- Phase A: stage exp weights + byte offsets for tc edges ----
        for (int lt = lane; lt < tcPad; lt += 64) {
            bool act = (lt < tc);
            int j = s0 + base + lt;
            int c = act ? cols[j] : 0;
            int rsel = (j >= b1) + (j >= b2) + (j >= b3);
            int fi = rbase + rsel; if (fi >= Nn) fi = Nn - 1;
            float4 f1r = f1[fi];
            float4 f2v = f2[c];
            float l0 = f1r.x + f2v.x; l0 = fmaxf(l0, ALPHA * l0);
            float l1 = f1r.y + f2v.y; l1 = fmaxf(l1, ALPHA * l1);
            float l2 = f1r.z + f2v.z; l2 = fmaxf(l2, ALPHA * l2);
            float l3 = f1r.w + f2v.w; l3 = fmaxf(l3, ALPHA * l3);
            float e0 = act ? __expf(l0) : 0.f;
            float e1 = act ? __expf(l1) : 0.f;
            float e2 = act ? __expf(l2) : 0.f;
            float e3 = act ? __expf(l3) : 0.f;
            asm volatile("s_waitcnt lgkmcnt(0)" ::: "memory");  // prior-chunk reads done
            *(float4*)&eLw[lt * 4] = make_float4(e0, e1, e2, e3);
            vLw[lt] = (uint)c << 8;
        }
        asm volatile("s_waitcnt lgkmcnt(0)" ::: "memory");      // stage visible

        // ---- Phase B: per-slot dual-stream edge walk ----
        int lo = sB - s0 - base; lo = (lo < 0) ? 0 : ((lo > tc) ? tc : lo);
        int hi = eB - s0 - base; hi = (hi < 0) ? 0 : ((hi > tc) ? tc : hi);
        int g = lo;
#pragma unroll 2
        for (; g + 1 < hi; g += 2) {
            float eA = eLw[g * 4 + hsel];
            float eB_ = eLw[g * 4 + 4 + hsel];
            uint  voA = vLw[g] + laneOff;
            uint  voB = vLw[g + 1] + laneOff;
            uint4 vA = *(const uint4*)(ftsB + voA);
            uint4 vB = *(const uint4*)(ftsB + voB);
            dsA += eA; dsB += eB_;
            float ve;
            ve = __uint_as_float(vA.x << 16);          accA[0] = fmaf(eA, ve, accA[0]);
            ve = __uint_as_float(vA.x & 0xffff0000u);  accA[1] = fmaf(eA, ve, accA[1]);
            ve = __uint_as_float(vA.y << 16);          accA[2] = fmaf(eA, ve, accA[2]);
            ve = __uint_as_float(vA.y & 0xffff0000u);  accA[3] = fmaf(eA, ve, accA[3]);
            ve = __uint_as_float(vA.z << 16);          accA[4] = fmaf(eA, ve, accA[4]);
            ve = __uint_as_float(vA.z & 0xffff0000u);  accA[5] = fmaf(eA, ve, accA[5]);
            ve = __uint_as_float(vA.w << 16);          accA[6] = fmaf(eA, ve, accA[6]);
            ve = __uint_as_float(vA.w & 0xffff0000u);  accA[7] = fmaf(eA, ve, accA[7]);
            ve = __uint_as_float(vB.x << 16);          accB[0] = fmaf(eB_, ve, accB[0]);
            ve = __uint_as_float(vB.x & 0xffff0000u);  accB[1] = fmaf(eB_, ve, accB[1]);
            ve = __uint_as_float(vB.y << 16);          accB[2] = fmaf(eB_, ve, accB[2]);
            ve = __uint_as_float(vB.y & 0xffff0000u);  accB[3] = fmaf(eB_, ve, accB[3]);
            ve = __uint_as_float(vB.z << 16);          accB[4] = fmaf(eB_, ve, accB[4]);
            ve = __uint_as_float(vB.z & 0xffff0000u);  accB[5] = fmaf(eB_, ve, accB[5]);
            ve = __uint_as_float(vB.w << 16);          accB[6] = fmaf(eB_, ve, accB[6]);
            ve = __uint_as_float(vB.w & 0xffff0000u);  accB[7] = fmaf(eB_, ve, accB[7]);
        }
        if (g < hi) {   // odd tail
            float eA = eLw[g * 4 + hsel];
            uint  voA = vLw[g] + laneOff;
            uint4 vA = *(const uint4*)(ftsB + voA);
            dsA += eA;
            float ve;
            ve = __uint_as_float(vA.x << 16);          accA[0] = fmaf(eA, ve, accA[0]);
            ve = __uint_as_float(vA.x & 0xffff0000u);  accA[1] = fmaf(eA, ve, accA[1]);
            ve = __uint_as_float(vA.y << 16);          accA[2] = fmaf(eA, ve, accA[2]);
            ve = __uint_as_float(vA.y & 0xffff0000u);  accA[3] = fmaf(eA, ve, accA[3]);
            ve = __uint_as_float(vA.z << 16);          accA[4] = fmaf(eA, ve, accA[4]);
            ve = __uint_as_float(vA.z & 0xffff0000u);  accA[5] = fmaf(eA, ve, accA[5]);
            ve = __uint_as_float(vA.w << 16);          accA[6] = fmaf(eA, ve, accA[6]);
            ve = __uint_as_float(vA.w & 0xffff0000u);  accA[7] = fmaf(eA, ve, accA[7]);
        }
    }

    // ---- epilogue: ds is the full denominator for this lane's head ----
    float ds = dsA + dsB;
    float dsel = (degTot > 0) ? ds : 1.f;
    float rinv = 1.0f / dsel;
    float o[8];
#pragma unroll
    for (int i = 0; i < 8; i++) {
        float v = (accA[i] + accB[i]) * rinv;
        o[i] = (v > 0.f) ? v : (__expf(v) - 1.0f);
    }
    if (rowAct) {
        float4* dst = (float4*)(out + (size_t)myr * 128 + sub * 8);
        dst[0] = make_float4(o[0], o[1], o[2], o[3]);
        dst[1] = make_float4(o[4], o[5], o[6], o[7]);
    }
}

// ---------------------------------------------------------------------------------
extern "C" void kernel_launch(void* const* d_in, const int* in_sizes, int n_in,
                              void* d_out, int out_size, void* d_ws, size_t ws_size,
                              hipStream_t stream)
{
    const float* x   = (const float*)d_in[0];
    const float* W   = (const float*)d_in[1];
    const float* a1  = (const float*)d_in[2];
    const float* b1  = (const float*)d_in[3];
    const float* a2  = (const float*)d_in[4];
    const float* b2  = (const float*)d_in[5];
    const int*   erow = (const int*)d_in[6];
    const int*   ecol = (const int*)d_in[7];
    float* out = (float*)d_out;

    const int N = in_sizes[0] / 256;   // 100000
    const int E = in_sizes[6];         // 1600000
    const int NB = (N + 255) >> 8;

    char*  ws  = (char*)d_ws;
    size_t off = 0;
    auto carve = [&](size_t bytes) -> char* {
        char* p = ws + off;
        off += (bytes + 255) & ~(size_t)255;
        return p;
    };
    ushort* fts2      = (ushort*)carve((size_t)N * 128 * 2);
    ushort* Wt        = (ushort*)carve((size_t)128 * 256 * 2);
    float*  f1        = (float*)carve((size_t)N * 4 * 4);
    float*  f2        = (float*)carve((size_t)N * 4 * 4);
    int*    row_start = (int*)carve(((size_t)N + 1) * 4);
    int*    bcnt      = (int*)carve(512 * 4);
    int*    base      = (int*)carve(513 * 4);
    int*    bcursor   = (int*)carve(512 * 4);
    int*    col_sorted= (int*)carve((size_t)E * 4);
    uint*   part      = (uint*)carve((size_t)E * 4);
    (void)ws_size;

    k_wprep<<<128, 256, 0, stream>>>(W, Wt);
    k_gemm<<<(N + 127) / 128, 256, 0, stream>>>(x, Wt, a1, b1, a2, b2, fts2, f1, f2, N);

    hipMemsetAsync(bcnt, 0, 512 * 4, stream);
    int npb = (E + PB_EDGES - 1) / PB_EDGES;
    k_phist<<<npb, 256, 0, stream>>>(erow, bcnt, E, NB);
    k_scan_buckets<<<1, 256, 0, stream>>>(bcnt, base, bcursor, NB, E);
    k_pscatter<<<npb, 256, 0, stream>>>(erow, ecol, bcursor, part, E);
    k_bucket<<<NB, 256, 0, stream>>>(part, base, row_start, col_sorted, N, NB, E);

    // 16 rows per block (4 waves x 4 rows)
    k_gat_row<<<(N + 15) / 16, 256, 0, stream>>>(fts2, (const float4*)f1, (const float4*)f2,
                                                 row_start, col_sorted, out, N);
}